// Round 3
// baseline (945.791 us; speedup 1.0000x reference)
//
#include <hip/hip_runtime.h>

typedef unsigned short u16;
typedef __bf16 bf16x8 __attribute__((ext_vector_type(8)));
typedef float floatx4 __attribute__((ext_vector_type(4)));

#define B_ 2
#define L_ 2048
#define S_ 2048
#define D_ 512
#define H_ 8

static __device__ __forceinline__ u16 f2bf(float f) {
  union { float f; unsigned u; } v; v.f = f;
  unsigned u = v.u;
  return (u16)((u + 0x7FFFu + ((u >> 16) & 1u)) >> 16);  // RNE
}
static __device__ __forceinline__ float bf2f(u16 h) {
  union { unsigned u; float f; } v; v.u = ((unsigned)h) << 16;
  return v.f;
}

// ---------------------------------------------------------------------------
// QKV projection GEMM: C[m][n] = sum_k A[m][k] * W[n][k]   (M=4096,N=512,K=512)
// z: 0 queries->qb (bf16), 1 keys->kb (bf16), 2 values->vb (bf16,+bv)
// ---------------------------------------------------------------------------
__global__ __launch_bounds__(256) void qkv_gemm(
    const float* __restrict__ Qin, const float* __restrict__ Kin, const float* __restrict__ Vin,
    const float* __restrict__ Wq, const float* __restrict__ Wk, const float* __restrict__ Wv,
    const float* __restrict__ bv,
    u16* __restrict__ qo, u16* __restrict__ ko, u16* __restrict__ vo)
{
  __shared__ u16 As[128][72];
  __shared__ u16 Bs[128][72];
  const int z = blockIdx.z;
  const float* A = (z == 0) ? Qin : (z == 1) ? Kin : Vin;
  const float* W = (z == 0) ? Wq : (z == 1) ? Wk : Wv;
  const int tid = threadIdx.x;
  const int m0 = blockIdx.y * 128;
  const int n0 = blockIdx.x * 128;
  const int lane = tid & 63, w = tid >> 6;
  const int ml = lane & 15, kl = lane >> 4;
  const int mqw = (w >> 1) * 64, nq = (w & 1) * 64;
  const int srow = tid >> 4, scg = tid & 15;

  floatx4 acc[4][4] = {};

  for (int k0 = 0; k0 < 512; k0 += 64) {
#pragma unroll
    for (int i = 0; i < 8; ++i) {
      const int r = srow + i * 16;
      float4 av = *(const float4*)&A[(size_t)(m0 + r) * 512 + k0 + scg * 4];
      ushort4 ua; ua.x = f2bf(av.x); ua.y = f2bf(av.y); ua.z = f2bf(av.z); ua.w = f2bf(av.w);
      *(ushort4*)&As[r][scg * 4] = ua;
      float4 wv = *(const float4*)&W[(size_t)(n0 + r) * 512 + k0 + scg * 4];
      ushort4 uw; uw.x = f2bf(wv.x); uw.y = f2bf(wv.y); uw.z = f2bf(wv.z); uw.w = f2bf(wv.w);
      *(ushort4*)&Bs[r][scg * 4] = uw;
    }
    __syncthreads();
#pragma unroll
    for (int kk = 0; kk < 64; kk += 32) {
      bf16x8 af[4], bfv[4];
#pragma unroll
      for (int i = 0; i < 4; ++i) af[i] = *(const bf16x8*)&As[mqw + i * 16 + ml][kk + kl * 8];
#pragma unroll
      for (int j = 0; j < 4; ++j) bfv[j] = *(const bf16x8*)&Bs[nq + j * 16 + ml][kk + kl * 8];
#pragma unroll
      for (int i = 0; i < 4; ++i)
#pragma unroll
        for (int j = 0; j < 4; ++j)
          acc[i][j] = __builtin_amdgcn_mfma_f32_16x16x32_bf16(af[i], bfv[j], acc[i][j], 0, 0, 0);
    }
    __syncthreads();
  }
#pragma unroll
  for (int i = 0; i < 4; ++i)
#pragma unroll
    for (int j = 0; j < 4; ++j) {
      const int gc = n0 + nq + j * 16 + ml;
#pragma unroll
      for (int r = 0; r < 4; ++r) {
        const int gr = m0 + mqw + i * 16 + kl * 4 + r;
        float v = acc[i][j][r];
        if (z == 0)      qo[(size_t)gr * 512 + gc] = f2bf(v);
        else if (z == 1) ko[(size_t)gr * 512 + gc] = f2bf(v);
        else             vo[(size_t)gr * 512 + gc] = f2bf(v + bv[gc]);
      }
    }
}

// ---------------------------------------------------------------------------
// mixed_q: mq[b][h][l][e] = bf16( qb[b][l][e] * mixing[h][e] )
// ---------------------------------------------------------------------------
__global__ __launch_bounds__(256) void mixq_kernel(
    const u16* __restrict__ qb, const float* __restrict__ mixing, u16* __restrict__ mq)
{
  __shared__ float mixs[8 * 512];
  const int tid = threadIdx.x;
#pragma unroll
  for (int i = 0; i < 4; ++i)
    *(float4*)&mixs[(tid + i * 256) * 4] = *(const float4*)&mixing[(tid + i * 256) * 4];
  __syncthreads();
  const size_t unit = (size_t)blockIdx.x * 256 + tid;
  const size_t el = unit * 8;
  const int e = (int)(el & 511);
  const size_t bl = el >> 9;
  const int b = (int)(bl >> 11);
  const int l = (int)(bl & 2047);
  uint4 qv = *(const uint4*)&qb[el];
  const float q0 = bf2f((u16)(qv.x & 0xFFFFu)), q1 = bf2f((u16)(qv.x >> 16));
  const float q2 = bf2f((u16)(qv.y & 0xFFFFu)), q3 = bf2f((u16)(qv.y >> 16));
  const float q4 = bf2f((u16)(qv.z & 0xFFFFu)), q5 = bf2f((u16)(qv.z >> 16));
  const float q6 = bf2f((u16)(qv.w & 0xFFFFu)), q7 = bf2f((u16)(qv.w >> 16));
#pragma unroll
  for (int h = 0; h < 8; ++h) {
    const float* mp = &mixs[h * 512 + e];
    uint4 o;
    o.x = (unsigned)f2bf(q0 * mp[0]) | ((unsigned)f2bf(q1 * mp[1]) << 16);
    o.y = (unsigned)f2bf(q2 * mp[2]) | ((unsigned)f2bf(q3 * mp[3]) << 16);
    o.z = (unsigned)f2bf(q4 * mp[4]) | ((unsigned)f2bf(q5 * mp[5]) << 16);
    o.w = (unsigned)f2bf(q6 * mp[6]) | ((unsigned)f2bf(q7 * mp[7]) << 16);
    *(uint4*)&mq[(((size_t)b * 8 + h) * 2048 + l) * 512 + e] = o;
  }
}

// ---------------------------------------------------------------------------
// Output projection GEMM: out[m][n] = sum_k ctx[m][k]*Wd[n][k] + bd[n]
// ---------------------------------------------------------------------------
__global__ __launch_bounds__(256) void out_gemm(
    const float* __restrict__ A, const float* __restrict__ W,
    const float* __restrict__ bias, float* __restrict__ out)
{
  __shared__ u16 As[128][72];
  __shared__ u16 Bs[128][72];
  const int tid = threadIdx.x;
  const int m0 = blockIdx.y * 128;
  const int n0 = blockIdx.x * 128;
  const int lane = tid & 63, w = tid >> 6;
  const int ml = lane & 15, kl = lane >> 4;
  const int mqw = (w >> 1) * 64, nq = (w & 1) * 64;
  const int srow = tid >> 4, scg = tid & 15;

  floatx4 acc[4][4] = {};

  for (int k0 = 0; k0 < 512; k0 += 64) {
#pragma unroll
    for (int i = 0; i < 8; ++i) {
      const int r = srow + i * 16;
      float4 av = *(const float4*)&A[(size_t)(m0 + r) * 512 + k0 + scg * 4];
      ushort4 ua; ua.x = f2bf(av.x); ua.y = f2bf(av.y); ua.z = f2bf(av.z); ua.w = f2bf(av.w);
      *(ushort4*)&As[r][scg * 4] = ua;
      float4 wv = *(const float4*)&W[(size_t)(n0 + r) * 512 + k0 + scg * 4];
      ushort4 uw; uw.x = f2bf(wv.x); uw.y = f2bf(wv.y); uw.z = f2bf(wv.z); uw.w = f2bf(wv.w);
      *(ushort4*)&Bs[r][scg * 4] = uw;
    }
    __syncthreads();
#pragma unroll
    for (int kk = 0; kk < 64; kk += 32) {
      bf16x8 af[4], bfv[4];
#pragma unroll
      for (int i = 0; i < 4; ++i) af[i] = *(const bf16x8*)&As[mqw + i * 16 + ml][kk + kl * 8];
#pragma unroll
      for (int j = 0; j < 4; ++j) bfv[j] = *(const bf16x8*)&Bs[nq + j * 16 + ml][kk + kl * 8];
#pragma unroll
      for (int i = 0; i < 4; ++i)
#pragma unroll
        for (int j = 0; j < 4; ++j)
          acc[i][j] = __builtin_amdgcn_mfma_f32_16x16x32_bf16(af[i], bfv[j], acc[i][j], 0, 0, 0);
    }
    __syncthreads();
  }
#pragma unroll
  for (int i = 0; i < 4; ++i)
#pragma unroll
    for (int j = 0; j < 4; ++j) {
      const int gc = n0 + nq + j * 16 + ml;
#pragma unroll
      for (int r = 0; r < 4; ++r) {
        const int gr = m0 + mqw + i * 16 + kl * 4 + r;
        out[(size_t)gr * 512 + gc] = acc[i][j][r] + bias[gc];
      }
    }
}

// ---------------------------------------------------------------------------
// Content bias: cb[b][h][s] = sum_d keys[b][s][d] * Wcb[h][d]
// ---------------------------------------------------------------------------
__global__ __launch_bounds__(256) void cb_kernel(
    const float* __restrict__ keys, const float* __restrict__ Wcb, float* __restrict__ cbuf)
{
  __shared__ float Wl[8 * 512];
  const int tid = threadIdx.x;
#pragma unroll
  for (int i = 0; i < 4; ++i) {
    const int idx = tid + i * 256;
    *(float4*)&Wl[idx * 4] = *(const float4*)&Wcb[idx * 4];
  }
  __syncthreads();
  const int w = tid >> 6, lane = tid & 63;
  const int rowid = blockIdx.x * 4 + w;
  const int b = rowid >> 11, s = rowid & 2047;
  const float* kr = keys + (size_t)rowid * 512;
  float acc[8] = {0.f, 0.f, 0.f, 0.f, 0.f, 0.f, 0.f, 0.f};
  for (int e = lane; e < 512; e += 64) {
    const float kv = kr[e];
#pragma unroll
    for (int hh = 0; hh < 8; ++hh) acc[hh] += kv * Wl[hh * 512 + e];
  }
#pragma unroll
  for (int hh = 0; hh < 8; ++hh) {
#pragma unroll
    for (int off = 32; off > 0; off >>= 1) acc[hh] += __shfl_xor(acc[hh], off, 64);
  }
  if (lane == 0) {
#pragma unroll
    for (int hh = 0; hh < 8; ++hh)
      cbuf[((size_t)b * 8 + hh) * 2048 + s] = acc[hh];
  }
}

// ---------------------------------------------------------------------------
// Transpose v: vb [B][S][512] bf16 -> vT [B][512][S] bf16
// ---------------------------------------------------------------------------
__global__ __launch_bounds__(256) void transpose_v(
    const u16* __restrict__ vb, u16* __restrict__ vT)
{
  __shared__ u16 t[64][72];
  const int tid = threadIdx.x;
  const int e0 = blockIdx.x * 64;
  const int s0 = blockIdx.y * 64;
  const int b = blockIdx.z;
  const int rr = tid >> 3, g = tid & 7;
#pragma unroll
  for (int i = 0; i < 2; ++i) {
    const int r = rr + i * 32;
    *(uint4*)&t[r][g * 8] = *(const uint4*)&vb[((size_t)b * S_ + s0 + r) * 512 + e0 + g * 8];
  }
  __syncthreads();
#pragma unroll
  for (int i = 0; i < 2; ++i) {
    const int er = rr + i * 32;
    uint4 o;
    o.x = (unsigned)t[g * 8 + 0][er] | ((unsigned)t[g * 8 + 1][er] << 16);
    o.y = (unsigned)t[g * 8 + 2][er] | ((unsigned)t[g * 8 + 3][er] << 16);
    o.z = (unsigned)t[g * 8 + 4][er] | ((unsigned)t[g * 8 + 5][er] << 16);
    o.w = (unsigned)t[g * 8 + 6][er] | ((unsigned)t[g * 8 + 7][er] << 16);
    *(uint4*)&vT[((size_t)b * 512 + e0 + er) * S_ + s0 + g * 8] = o;
  }
}

// ---------------------------------------------------------------------------
// FUSED scores + softmax + probs + ctx.  One block = (bh, 16 l-rows).
// Wave w owns score cols [w*512, w*512+512).  A-frags (16 rows x K=512 of mq)
// are register-resident (64 VGPRs); B streams from L2-resident kb directly in
// B-fragment layout -> no LDS in the scores loop.  Raw scores never touch HBM.
// ---------------------------------------------------------------------------
__global__ __launch_bounds__(256, 2) void fused_attn(
    const u16* __restrict__ mq, const u16* __restrict__ kb,
    const float* __restrict__ cbuf, const u16* __restrict__ vT,
    float* __restrict__ probs, float* __restrict__ ctx)
{
  __shared__ u16 Ps[16][1032];     // P half-tile (1024 cols) for ctx A-frags
  __shared__ float redm[16][4];    // cross-wave max
  __shared__ float reds[16][4];    // cross-wave sum
  const int tid = threadIdx.x;
  const int bh = blockIdx.y, b = bh >> 3, h = bh & 7;
  const int l0 = blockIdx.x * 16;
  const int lane = tid & 63, w = tid >> 6;
  const int ml = lane & 15, kl = lane >> 4;
  const int n0w = w * 512;

  // --- A-fragments: rows l0..l0+15 of mq[bh], all K=512, in registers ---
  const u16* arow = mq + ((size_t)bh * L_ + l0 + ml) * 512 + kl * 8;
  bf16x8 af[16];
#pragma unroll
  for (int ks = 0; ks < 16; ++ks)
    af[ks] = *(const bf16x8*)(arow + ks * 32);

  const u16* kbb = kb + (size_t)b * S_ * 512;
  const float* cbp = cbuf + (size_t)bh * S_;

  // --- scores: 32 n-tiles of 16 cols; raw bf16 kept in pr[], max tracked ---
  unsigned pr[64];
  float mx[4] = {-3.0e38f, -3.0e38f, -3.0e38f, -3.0e38f};
#pragma unroll
  for (int t = 0; t < 32; ++t) {
    const u16* brow = kbb + (size_t)(n0w + t * 16 + ml) * 512 + kl * 8;
    floatx4 acc = {};
#pragma unroll
    for (int ks = 0; ks < 16; ++ks) {
      bf16x8 bfv = *(const bf16x8*)(brow + ks * 32);
      acc = __builtin_amdgcn_mfma_f32_16x16x32_bf16(af[ks], bfv, acc, 0, 0, 0);
    }
    const float cbv = cbp[n0w + t * 16 + ml];
    float s0 = (acc[0] + cbv) * 0.125f;
    float s1 = (acc[1] + cbv) * 0.125f;
    float s2 = (acc[2] + cbv) * 0.125f;
    float s3 = (acc[3] + cbv) * 0.125f;
    mx[0] = fmaxf(mx[0], s0); mx[1] = fmaxf(mx[1], s1);
    mx[2] = fmaxf(mx[2], s2); mx[3] = fmaxf(mx[3], s3);
    pr[2 * t]     = (unsigned)f2bf(s0) | ((unsigned)f2bf(s1) << 16);
    pr[2 * t + 1] = (unsigned)f2bf(s2) | ((unsigned)f2bf(s3) << 16);
  }

  // --- row max: shuffle over ml, then cross-wave via LDS ---
#pragma unroll
  for (int r = 0; r < 4; ++r)
#pragma unroll
    for (int off = 1; off < 16; off <<= 1)
      mx[r] = fmaxf(mx[r], __shfl_xor(mx[r], off, 64));
  if (ml == 0) {
#pragma unroll
    for (int r = 0; r < 4; ++r) redm[kl * 4 + r][w] = mx[r];
  }
  __syncthreads();
#pragma unroll
  for (int r = 0; r < 4; ++r) {
    const float* rm = redm[kl * 4 + r];
    mx[r] = fmaxf(fmaxf(rm[0], rm[1]), fmaxf(rm[2], rm[3]));
  }

  // --- row sum of exp ---
  float ls[4] = {0.f, 0.f, 0.f, 0.f};
#pragma unroll
  for (int t = 0; t < 32; ++t) {
    const unsigned u0 = pr[2 * t], u1 = pr[2 * t + 1];
    ls[0] += __expf(bf2f((u16)(u0 & 0xFFFFu)) - mx[0]);
    ls[1] += __expf(bf2f((u16)(u0 >> 16))     - mx[1]);
    ls[2] += __expf(bf2f((u16)(u1 & 0xFFFFu)) - mx[2]);
    ls[3] += __expf(bf2f((u16)(u1 >> 16))     - mx[3]);
  }
#pragma unroll
  for (int r = 0; r < 4; ++r)
#pragma unroll
    for (int off = 1; off < 16; off <<= 1)
      ls[r] += __shfl_xor(ls[r], off, 64);
  if (ml == 0) {
#pragma unroll
    for (int r = 0; r < 4; ++r) reds[kl * 4 + r][w] = ls[r];
  }
  __syncthreads();
  float rl[4];
#pragma unroll
  for (int r = 0; r < 4; ++r) {
    const float* rs = reds[kl * 4 + r];
    rl[r] = 1.0f / (rs[0] + rs[1] + rs[2] + rs[3]);
  }

  // --- normalize (fp32 re-exp), write probs, repack bf16 into pr ---
  float* Pg = probs + ((size_t)bh * L_ + l0) * S_;
#pragma unroll
  for (int t = 0; t < 32; ++t) {
    const int col = n0w + t * 16 + ml;
    const unsigned u0 = pr[2 * t], u1 = pr[2 * t + 1];
    float p0 = __expf(bf2f((u16)(u0 & 0xFFFFu)) - mx[0]) * rl[0];
    float p1 = __expf(bf2f((u16)(u0 >> 16))     - mx[1]) * rl[1];
    float p2 = __expf(bf2f((u16)(u1 & 0xFFFFu)) - mx[2]) * rl[2];
    float p3 = __expf(bf2f((u16)(u1 >> 16))     - mx[3]) * rl[3];
    Pg[(size_t)(kl * 4 + 0) * S_ + col] = p0;
    Pg[(size_t)(kl * 4 + 1) * S_ + col] = p1;
    Pg[(size_t)(kl * 4 + 2) * S_ + col] = p2;
    Pg[(size_t)(kl * 4 + 3) * S_ + col] = p3;
    pr[2 * t]     = (unsigned)f2bf(p0) | ((unsigned)f2bf(p1) << 16);
    pr[2 * t + 1] = (unsigned)f2bf(p2) | ((unsigned)f2bf(p3) << 16);
  }

  // --- ctx = P(16x2048) @ Vhead(2048x64), in two 1024-col halves ---
  floatx4 acc = {};
  const u16* vrow = vT + ((size_t)b * 512 + h * 64 + w * 16 + ml) * (size_t)S_ + kl * 8;
#pragma unroll
  for (int half = 0; half < 2; ++half) {
    __syncthreads();                       // Ps free before overwrite
    if ((w >> 1) == half) {
      const int cbase = (w & 1) * 512;
#pragma unroll
      for (int t = 0; t < 32; ++t) {
        const int col = cbase + t * 16 + ml;
        const unsigned u0 = pr[2 * t], u1 = pr[2 * t + 1];
        Ps[kl * 4 + 0][col] = (u16)(u0 & 0xFFFFu);
        Ps[kl * 4 + 1][col] = (u16)(u0 >> 16);
        Ps[kl * 4 + 2][col] = (u16)(u1 & 0xFFFFu);
        Ps[kl * 4 + 3][col] = (u16)(u1 >> 16);
      }
    }
    __syncthreads();
    const u16* vk = vrow + half * 1024;
#pragma unroll
    for (int k0 = 0; k0 < 1024; k0 += 32) {
      bf16x8 a  = *(const bf16x8*)&Ps[ml][k0 + kl * 8];
      bf16x8 bb = *(const bf16x8*)&vk[k0];
      acc = __builtin_amdgcn_mfma_f32_16x16x32_bf16(a, bb, acc, 0, 0, 0);
    }
  }
#pragma unroll
  for (int r = 0; r < 4; ++r)
    ctx[((size_t)b * L_ + l0 + kl * 4 + r) * 512 + h * 64 + w * 16 + ml] = acc[r];
}

// ---------------------------------------------------------------------------
extern "C" void kernel_launch(void* const* d_in, const int* in_sizes, int n_in,
                              void* d_out, int out_size, void* d_ws, size_t ws_size,
                              hipStream_t stream) {
  const float* queries = (const float*)d_in[0];
  const float* keys    = (const float*)d_in[1];
  const float* values  = (const float*)d_in[2];
  const float* Wq  = (const float*)d_in[4];
  const float* Wk  = (const float*)d_in[5];
  const float* Wv  = (const float*)d_in[6];
  const float* bv  = (const float*)d_in[7];
  const float* Wcb = (const float*)d_in[8];
  const float* mixing = (const float*)d_in[9];
  const float* Wd  = (const float*)d_in[10];
  const float* bd  = (const float*)d_in[11];

  float* out   = (float*)d_out;                         // [B,L,512] fp32
  float* probs = out + (size_t)B_ * L_ * 512;           // [B,H,L,S] fp32

  char* ws = (char*)d_ws;
  u16*   qb  = (u16*)(ws);                              //  4 MB  bf16 [B*L,512]
  u16*   kb  = (u16*)(ws + (size_t)4  * 1024 * 1024);   //  4 MB  bf16 [B*S,512]
  u16*   vb  = (u16*)(ws + (size_t)8  * 1024 * 1024);   //  4 MB  bf16 [B*S,512]
  u16*   vT  = (u16*)(ws + (size_t)12 * 1024 * 1024);   //  4 MB  bf16 [B,512,S]
  float* cbuf= (float*)(ws + (size_t)16 * 1024 * 1024); // 128 KB fp32 [B,H,S]
  float* ctx = (float*)(ws + (size_t)17 * 1024 * 1024); //  8 MB  fp32 [B*L,512]
  u16*   mq  = (u16*)(ws + (size_t)25 * 1024 * 1024);   // 32 MB  bf16 [B,H,L,512]

  hipLaunchKernelGGL(qkv_gemm, dim3(4, 32, 3), dim3(256), 0, stream,
                     queries, keys, values, Wq, Wk, Wv, bv, qb, kb, vb);
  hipLaunchKernelGGL(mixq_kernel, dim3(1024), dim3(256), 0, stream, qb, mixing, mq);
  hipLaunchKernelGGL(cb_kernel, dim3(1024), dim3(256), 0, stream, keys, Wcb, cbuf);
  hipLaunchKernelGGL(transpose_v, dim3(8, 32, 2), dim3(256), 0, stream, vb, vT);
  hipLaunchKernelGGL(fused_attn, dim3(128, 16), dim3(256), 0, stream,
                     mq, kb, cbuf, vT, probs, ctx);
  hipLaunchKernelGGL(out_gemm, dim3(4, 32, 1), dim3(256), 0, stream,
                     ctx, Wd, bd, out);
}